// Round 9
// baseline (198.649 us; speedup 1.0000x reference)
//
#include <hip/hip_runtime.h>
#include <stdint.h>

typedef unsigned short u16;
typedef float f32x4 __attribute__((ext_vector_type(4)));
typedef __bf16 bf16x8 __attribute__((ext_vector_type(8)));
typedef short s16x4 __attribute__((ext_vector_type(4)));

__device__ __forceinline__ u16 f2bf(float f) {
  union { float f; uint32_t u; } c; c.f = f;
  uint32_t u = c.u;
  u += 0x7fffu + ((u >> 16) & 1u);   // RNE
  return (u16)(u >> 16);
}

// pack two fp32 into one dword of 2 bf16 (truncation)
__device__ __forceinline__ uint32_t pkbf(float a, float b) {
  union { float f; uint32_t u; } ua, ub; ua.f = a; ub.f = b;
  return __builtin_amdgcn_perm(ub.u, ua.u, 0x07060302u);
}

// global -> LDS direct copy, 16B per lane. LDS dest = wave-uniform base + lane*16.
#define GLOAD_LDS16(g, l)                                                              \
  __builtin_amdgcn_global_load_lds((__attribute__((address_space(1))) void*)(g),       \
                                   (__attribute__((address_space(3))) void*)(l), 16, 0, 0)

// ---------------------------------------------------------------- fused fp32->bf16
__global__ __launch_bounds__(256) void cvt_all(const float* __restrict__ x,
                                               const float* __restrict__ wq,
                                               const float* __restrict__ wk,
                                               const float* __restrict__ wv,
                                               const float* __restrict__ wo,
                                               u16* __restrict__ xb,
                                               u16* __restrict__ wqkvb,
                                               u16* __restrict__ wob) {
  int bx = blockIdx.x;
  const float* src;
  u16* dst;
  int i;
  if (bx < 4096) {
    src = x; dst = xb; i = bx * 256 + threadIdx.x;
  } else {
    int r = bx - 4096;
    int w = r >> 10;
    i = (r & 1023) * 256 + threadIdx.x;
    if (w == 0)      { src = wq; dst = wqkvb; }
    else if (w == 1) { src = wk; dst = wqkvb + 1048576; }
    else if (w == 2) { src = wv; dst = wqkvb + 2097152; }
    else             { src = wo; dst = wob; }
  }
  const float4 v = ((const float4*)src)[i];
  ushort4 o;
  o.x = f2bf(v.x); o.y = f2bf(v.y); o.z = f2bf(v.z); o.w = f2bf(v.w);
  ((ushort4*)dst)[i] = o;
}

// ---------------------------------------------------------------- QKV projection
// BK=64, XOR-swizzled LDS. C cols 0..1023 -> Q * (0.125*log2e), 1024..2047 -> K;
// 2048..3071 -> Vt [1024 hd x 4096 tok] (pre-transposed V)
__global__ __launch_bounds__(256) void gemm_qkv(const u16* __restrict__ A,
                                                const u16* __restrict__ B,
                                                u16* __restrict__ QKb,
                                                u16* __restrict__ Vt) {
  const int K = 1024;
  __shared__ __align__(16) u16 sA[128 * 64];
  __shared__ __align__(16) u16 sB[128 * 64];
  const int tid = threadIdx.x;
  const int lane = tid & 63;
  const int wave = tid >> 6;
  const int quad = lane >> 4, l16 = lane & 15;
  const int wm = (wave >> 1) * 64, wn = (wave & 1) * 64;
  const int bm = blockIdx.y * 128, bn = blockIdx.x * 128;

  f32x4 acc[4][4];
#pragma unroll
  for (int i = 0; i < 4; i++)
#pragma unroll
    for (int j = 0; j < 4; j++) acc[i][j] = (f32x4){0.f, 0.f, 0.f, 0.f};

  for (int k0 = 0; k0 < K; k0 += 64) {
#pragma unroll
    for (int k2 = 0; k2 < 4; k2++) {
      int c = k2 * 256 + tid;
      int row = c >> 3, c8 = (c & 7) ^ (row & 7);
      GLOAD_LDS16(A + (size_t)(bm + row) * K + k0 + c8 * 8, (char*)sA + c * 16);
      GLOAD_LDS16(B + (size_t)(bn + row) * K + k0 + c8 * 8, (char*)sB + c * 16);
    }
    __syncthreads();
    bf16x8 af[4][2], bfr[4][2];
#pragma unroll
    for (int mt = 0; mt < 4; mt++)
#pragma unroll
      for (int kh = 0; kh < 2; kh++) {
        int ra = wm + mt * 16 + l16;
        af[mt][kh] = *(const bf16x8*)&sA[ra * 64 + (((kh * 4 + quad) ^ (ra & 7)) * 8)];
        int rb = wn + mt * 16 + l16;
        bfr[mt][kh] = *(const bf16x8*)&sB[rb * 64 + (((kh * 4 + quad) ^ (rb & 7)) * 8)];
      }
#pragma unroll
    for (int mt = 0; mt < 4; mt++)
#pragma unroll
      for (int nt = 0; nt < 4; nt++) {
        acc[mt][nt] = __builtin_amdgcn_mfma_f32_16x16x32_bf16(af[mt][0], bfr[nt][0], acc[mt][nt], 0, 0, 0);
        acc[mt][nt] = __builtin_amdgcn_mfma_f32_16x16x32_bf16(af[mt][1], bfr[nt][1], acc[mt][nt], 0, 0, 0);
      }
    __syncthreads();
  }

  if (blockIdx.x < 16) {
    // Q gets 1/sqrt(d_k) * log2(e) folded in (softmax uses exp2)
    const float qs = (blockIdx.x < 8) ? 0.18033688011f : 1.0f;
#pragma unroll
    for (int mt = 0; mt < 4; mt++)
#pragma unroll
      for (int nt = 0; nt < 4; nt++)
#pragma unroll
        for (int r = 0; r < 4; r++) {
          int row = bm + wm + mt * 16 + quad * 4 + r;
          int col = bn + wn + nt * 16 + l16;
          QKb[(size_t)row * 2048 + col] = f2bf(acc[mt][nt][r] * qs);
        }
  } else {
#pragma unroll
    for (int mt = 0; mt < 4; mt++)
#pragma unroll
      for (int nt = 0; nt < 4; nt++) {
        int hd = (bn - 2048) + wn + nt * 16 + l16;
        int tok = bm + wm + mt * 16 + quad * 4;
        ushort4 o;
        o.x = f2bf(acc[mt][nt][0]);
        o.y = f2bf(acc[mt][nt][1]);
        o.z = f2bf(acc[mt][nt][2]);
        o.w = f2bf(acc[mt][nt][3]);
        *(ushort4*)&Vt[(size_t)hd * 4096 + tok] = o;
      }
  }
}

// ---------------------------------------------------------------- flash attention
// 128-thread blocks, BQ=64, 32 q/wave. LDS = 32 KB (no sQ: Q staged into sV1,
// frags hoisted, then buffer recycled) -> 4-5 blocks/CU. lsum computed by MFMA
// with a constant ones A-operand (no VALU adds, no final shuffle reduce).
__global__ __launch_bounds__(128, 2) void attn_fwd(const u16* __restrict__ QKb,
                                                   const u16* __restrict__ Vt,
                                                   u16* __restrict__ O) {
  const int bx = blockIdx.x;
  const int qt = bx >> 5;
  const int h  = (bx >> 1) & 15;
  const int b  = bx & 1;
  const int tid = threadIdx.x;    // 0..127
  const int lane = tid & 63;
  const int wave = tid >> 6;      // 0..1
  const int quad = lane >> 4, l16 = lane & 15;

  // 32 KB: sK[2] (16K) | sV[2] (16K). Q staged into sV1 pre-loop; sT reuses front.
  __shared__ __align__(16) u16 smem[16384];
  u16* sK0 = smem;
  u16* sK1 = smem + 4096;
  u16* sV0 = smem + 8192;
  u16* sV1 = smem + 12288;

  const int tok0 = b * 2048;
  const int q0 = qt * 64;
  const int colh = h * 64;

  // ---- stage Q (64x64) into sV1; K0 -> sK0; V0 -> sV0
#pragma unroll
  for (int k2 = 0; k2 < 4; k2++) {
    int c = k2 * 128 + tid;
    int row = c >> 3, c8 = (c & 7) ^ (row & 7);
    GLOAD_LDS16(QKb + (size_t)(tok0 + q0 + row) * 2048 + colh + c8 * 8,
                (char*)sV1 + c * 16);
    GLOAD_LDS16(QKb + (size_t)(tok0 + row) * 2048 + 1024 + colh + c8 * 8,
                (char*)sK0 + c * 16);
    GLOAD_LDS16(Vt + (size_t)(colh + row) * 4096 + tok0 + c8 * 8,
                (char*)sV0 + c * 16);
  }
  __syncthreads();

  // ---- hoist Q fragments: this wave's 32 q rows (2 subs of 16)
  bf16x8 aq[2][2];
#pragma unroll
  for (int sub = 0; sub < 2; sub++)
#pragma unroll
    for (int kh = 0; kh < 2; kh++) {
      int row = wave * 32 + sub * 16 + l16;
      aq[sub][kh] = *(const bf16x8*)&sV1[row * 64 + (((kh * 4 + quad) ^ (row & 7)) * 8)];
    }
  __syncthreads();   // all aq reads done before iter-0 prefetch overwrites sV1

  // ones A-operand for the lsum MFMA (bf16 1.0 x4)
  const s16x4 ones = (s16x4){0x3F80, 0x3F80, 0x3F80, 0x3F80};

  f32x4 oacc[2][4];
  f32x4 lacc[2];
#pragma unroll
  for (int sub = 0; sub < 2; sub++) {
    lacc[sub] = (f32x4){0.f, 0.f, 0.f, 0.f};
#pragma unroll
    for (int db = 0; db < 4; db++) oacc[sub][db] = (f32x4){0.f, 0.f, 0.f, 0.f};
  }

  int p = 0;
  for (int it = 0; it < 32; ++it) {
    u16* sKc = p ? sK1 : sK0;
    u16* sVc = p ? sV1 : sV0;
    if (it < 31) {
      u16* sKn = p ? sK0 : sK1;
      u16* sVn = p ? sV0 : sV1;
      const int nkv = (it + 1) * 64;
#pragma unroll
      for (int k2 = 0; k2 < 4; k2++) {
        int c = k2 * 128 + tid;
        int row = c >> 3, c8 = (c & 7) ^ (row & 7);
        GLOAD_LDS16(QKb + (size_t)(tok0 + nkv + row) * 2048 + 1024 + colh + c8 * 8,
                    (char*)sKn + c * 16);
        GLOAD_LDS16(Vt + (size_t)(colh + row) * 4096 + tok0 + nkv + c8 * 8,
                    (char*)sVn + c * 16);
      }
    }

    // K fragments (A-op of S^T: m=kv), b128 — shared by both subs
    bf16x8 kf[4][2];
#pragma unroll
    for (int nt = 0; nt < 4; nt++)
#pragma unroll
      for (int kh = 0; kh < 2; kh++) {
        int rr = nt * 16 + l16;
        kf[nt][kh] = *(const bf16x8*)&sKc[rr * 64 + (((kh * 4 + quad) ^ (rr & 7)) * 8)];
      }
    // V fragments (A-op of PV, K=16: m=d=l16, k=quad*4+i), in-lane b64 reads — shared
    s16x4 vf[4][4];
#pragma unroll
    for (int db = 0; db < 4; db++)
#pragma unroll
      for (int nt = 0; nt < 4; nt++) {
        int row = db * 16 + l16;
        int c16 = (nt * 2 + (quad >> 1)) ^ (row & 7);
        vf[db][nt] = *(const s16x4*)&sVc[row * 64 + c16 * 8 + (quad & 1) * 4];
      }

#pragma unroll
    for (int sub = 0; sub < 2; sub++) {
      // S^T = K Q^T : C rows = kv (nt*16+quad*4+r), cols = q (l16)
      float e[4][4];
#pragma unroll
      for (int nt = 0; nt < 4; nt++) {
        f32x4 c = (f32x4){0.f, 0.f, 0.f, 0.f};
        c = __builtin_amdgcn_mfma_f32_16x16x32_bf16(kf[nt][0], aq[sub][0], c, 0, 0, 0);
        c = __builtin_amdgcn_mfma_f32_16x16x32_bf16(kf[nt][1], aq[sub][1], c, 0, 0, 0);
#pragma unroll
        for (int r = 0; r < 4; r++) e[nt][r] = __builtin_amdgcn_exp2f(c[r]);
      }
      // PV: O^T += V^T P^T (K=16 B-layout == 16x16 C-layout -> in-lane pack);
      // lsum rows via ones-MFMA (every lane ends with lsum for q=l16).
#pragma unroll
      for (int nt = 0; nt < 4; nt++) {
        union { uint32_t u[2]; s16x4 v; } bb;
        bb.u[0] = pkbf(e[nt][0], e[nt][1]);
        bb.u[1] = pkbf(e[nt][2], e[nt][3]);
        lacc[sub] = __builtin_amdgcn_mfma_f32_16x16x16bf16_1k(ones, bb.v, lacc[sub], 0, 0, 0);
#pragma unroll
        for (int db = 0; db < 4; db++)
          oacc[sub][db] = __builtin_amdgcn_mfma_f32_16x16x16bf16_1k(vf[db][nt], bb.v, oacc[sub][db], 0, 0, 0);
      }
    }
    __syncthreads();   // buf p consumed by both waves; prefetch into p^1 drained
    p ^= 1;
  }

  // ---- normalize: lane already holds lsum for its q=l16 (all 4 lacc entries equal)
  float inv[2];
#pragma unroll
  for (int sub = 0; sub < 2; sub++) inv[sub] = 1.0f / lacc[sub][0];

  // ---- epilogue: O^T regs -> per-wave LDS tile [32 q][stride 68] -> coalesced store
  u16* sT = smem + wave * 2176;
#pragma unroll
  for (int sub = 0; sub < 2; sub++)
#pragma unroll
    for (int db = 0; db < 4; db++)
#pragma unroll
      for (int r = 0; r < 4; r++)
        sT[(sub * 16 + l16) * 68 + db * 16 + quad * 4 + r] = f2bf(oacc[sub][db][r] * inv[sub]);
  // wave-local RAW; compiler orders via lgkmcnt
#pragma unroll
  for (int k = 0; k < 4; k++) {
    int qrow = k * 8 + (lane >> 3);
    int cch = lane & 7;
    uint4 vrow = *(const uint4*)&sT[qrow * 68 + cch * 8];
    int tokr = tok0 + q0 + wave * 32 + qrow;
    *(uint4*)&O[(size_t)tokr * 1024 + colh + cch * 8] = vrow;
  }
}

// ---------------------------------------------------------------- final projection
// 128x64 tiles, BK=64 swizzled. A: O [4096x1024] bf16, B: wo [1024x1024] bf16.
__global__ __launch_bounds__(256) void gemm_out(const u16* __restrict__ A,
                                                const u16* __restrict__ B,
                                                float* __restrict__ C) {
  const int N = 1024, K = 1024;
  __shared__ __align__(16) u16 sA[128 * 64];
  __shared__ __align__(16) u16 sB[64 * 64];
  const int tid = threadIdx.x;
  const int lane = tid & 63;
  const int wave = tid >> 6;
  const int quad = lane >> 4, l16 = lane & 15;
  const int wm = (wave >> 1) * 64, wn = (wave & 1) * 32;
  const int bm = blockIdx.y * 128, bn = blockIdx.x * 64;

  f32x4 acc[4][2];
#pragma unroll
  for (int i = 0; i < 4; i++)
#pragma unroll
    for (int j = 0; j < 2; j++) acc[i][j] = (f32x4){0.f, 0.f, 0.f, 0.f};

  for (int k0 = 0; k0 < K; k0 += 64) {
#pragma unroll
    for (int k2 = 0; k2 < 4; k2++) {
      int c = k2 * 256 + tid;
      int row = c >> 3, c8 = (c & 7) ^ (row & 7);
      GLOAD_LDS16(A + (size_t)(bm + row) * K + k0 + c8 * 8, (char*)sA + c * 16);
    }
#pragma unroll
    for (int k2 = 0; k2 < 2; k2++) {
      int c = k2 * 256 + tid;
      int row = c >> 3, c8 = (c & 7) ^ (row & 7);
      GLOAD_LDS16(B + (size_t)(bn + row) * K + k0 + c8 * 8, (char*)sB + c * 16);
    }
    __syncthreads();
    bf16x8 af[4][2], bfr[2][2];
#pragma unroll
    for (int mt = 0; mt < 4; mt++)
#pragma unroll
      for (int kh = 0; kh < 2; kh++) {
        int ra = wm + mt * 16 + l16;
        af[mt][kh] = *(const bf16x8*)&sA[ra * 64 + (((kh * 4 + quad) ^ (ra & 7)) * 8)];
      }
#pragma unroll
    for (int nt = 0; nt < 2; nt++)
#pragma unroll
      for (int kh = 0; kh < 2; kh++) {
        int rb = wn + nt * 16 + l16;
        bfr[nt][kh] = *(const bf16x8*)&sB[rb * 64 + (((kh * 4 + quad) ^ (rb & 7)) * 8)];
      }
#pragma unroll
    for (int mt = 0; mt < 4; mt++)
#pragma unroll
      for (int nt = 0; nt < 2; nt++) {
        acc[mt][nt] = __builtin_amdgcn_mfma_f32_16x16x32_bf16(af[mt][0], bfr[nt][0], acc[mt][nt], 0, 0, 0);
        acc[mt][nt] = __builtin_amdgcn_mfma_f32_16x16x32_bf16(af[mt][1], bfr[nt][1], acc[mt][nt], 0, 0, 0);
      }
    __syncthreads();
  }

#pragma unroll
  for (int mt = 0; mt < 4; mt++)
#pragma unroll
    for (int nt = 0; nt < 2; nt++)
#pragma unroll
      for (int r = 0; r < 4; r++) {
        int row = bm + wm + mt * 16 + quad * 4 + r;
        int col = bn + wn + nt * 16 + l16;
        C[(size_t)row * N + col] = acc[mt][nt][r];
      }
}

// ---------------------------------------------------------------- launch
extern "C" void kernel_launch(void* const* d_in, const int* in_sizes, int n_in,
                              void* d_out, int out_size, void* d_ws, size_t ws_size,
                              hipStream_t stream) {
  const float* x  = (const float*)d_in[0];
  const float* wq = (const float*)d_in[1];
  const float* wk = (const float*)d_in[2];
  const float* wv = (const float*)d_in[3];
  const float* wo = (const float*)d_in[4];
  float* out = (float*)d_out;
  char* ws = (char*)d_ws;
  const size_t MB = 1u << 20;

  u16* xb    = (u16*)(ws);            // 8 MB  [4096 x 1024] bf16 x
  u16* wqkvb = (u16*)(ws + 8 * MB);   // 6 MB  [3072 x 1024]
  u16* wob   = (u16*)(ws + 14 * MB);  // 2 MB
  u16* QKb   = (u16*)(ws + 16 * MB);  // 16 MB [4096 x 2048] (Q*s | K)
  u16* Vtb   = (u16*)(ws + 32 * MB);  // 8 MB  [1024 hd x 4096 tok]
  u16* Ob    = xb;                    // alias: x dead after QKV gemm

  cvt_all<<<8192, 256, 0, stream>>>(x, wq, wk, wv, wo, xb, wqkvb, wob);

  gemm_qkv<<<dim3(24, 32), 256, 0, stream>>>(xb, wqkvb, QKb, Vtb);

  attn_fwd<<<1024, 128, 0, stream>>>(QKb, Vtb, Ob);

  gemm_out<<<dim3(16, 32), 256, 0, stream>>>(Ob, wob, out);
}

// Round 10
// 186.815 us; speedup vs baseline: 1.0633x; 1.0633x over previous
//
#include <hip/hip_runtime.h>
#include <stdint.h>

typedef unsigned short u16;
typedef float f32x4 __attribute__((ext_vector_type(4)));
typedef __bf16 bf16x8 __attribute__((ext_vector_type(8)));
typedef short s16x4 __attribute__((ext_vector_type(4)));

__device__ __forceinline__ u16 f2bf(float f) {
  union { float f; uint32_t u; } c; c.f = f;
  uint32_t u = c.u;
  u += 0x7fffu + ((u >> 16) & 1u);   // RNE
  return (u16)(u >> 16);
}

// pack two fp32 into one dword of 2 bf16 (truncation)
__device__ __forceinline__ uint32_t pkbf(float a, float b) {
  union { float f; uint32_t u; } ua, ub; ua.f = a; ub.f = b;
  return __builtin_amdgcn_perm(ub.u, ua.u, 0x07060302u);
}

// global -> LDS direct copy, 16B per lane. LDS dest = wave-uniform base + lane*16.
#define GLOAD_LDS16(g, l)                                                              \
  __builtin_amdgcn_global_load_lds((__attribute__((address_space(1))) void*)(g),       \
                                   (__attribute__((address_space(3))) void*)(l), 16, 0, 0)

// ---------------------------------------------------------------- fused fp32->bf16
__global__ __launch_bounds__(256) void cvt_all(const float* __restrict__ x,
                                               const float* __restrict__ wq,
                                               const float* __restrict__ wk,
                                               const float* __restrict__ wv,
                                               const float* __restrict__ wo,
                                               u16* __restrict__ xb,
                                               u16* __restrict__ wqkvb,
                                               u16* __restrict__ wob) {
  int bx = blockIdx.x;
  const float* src;
  u16* dst;
  int i;
  if (bx < 4096) {
    src = x; dst = xb; i = bx * 256 + threadIdx.x;
  } else {
    int r = bx - 4096;
    int w = r >> 10;
    i = (r & 1023) * 256 + threadIdx.x;
    if (w == 0)      { src = wq; dst = wqkvb; }
    else if (w == 1) { src = wk; dst = wqkvb + 1048576; }
    else if (w == 2) { src = wv; dst = wqkvb + 2097152; }
    else             { src = wo; dst = wob; }
  }
  const float4 v = ((const float4*)src)[i];
  ushort4 o;
  o.x = f2bf(v.x); o.y = f2bf(v.y); o.z = f2bf(v.z); o.w = f2bf(v.w);
  ((ushort4*)dst)[i] = o;
}

// ---------------------------------------------------------------- QKV projection
// BK=64, XOR-swizzled LDS. C cols 0..1023 -> Q * (0.125*log2e), 1024..2047 -> K;
// 2048..3071 -> Vt [1024 hd x 4096 tok] (pre-transposed V)
__global__ __launch_bounds__(256) void gemm_qkv(const u16* __restrict__ A,
                                                const u16* __restrict__ B,
                                                u16* __restrict__ QKb,
                                                u16* __restrict__ Vt) {
  const int K = 1024;
  __shared__ __align__(16) u16 sA[128 * 64];
  __shared__ __align__(16) u16 sB[128 * 64];
  const int tid = threadIdx.x;
  const int lane = tid & 63;
  const int wave = tid >> 6;
  const int quad = lane >> 4, l16 = lane & 15;
  const int wm = (wave >> 1) * 64, wn = (wave & 1) * 64;
  const int bm = blockIdx.y * 128, bn = blockIdx.x * 128;

  f32x4 acc[4][4];
#pragma unroll
  for (int i = 0; i < 4; i++)
#pragma unroll
    for (int j = 0; j < 4; j++) acc[i][j] = (f32x4){0.f, 0.f, 0.f, 0.f};

  for (int k0 = 0; k0 < K; k0 += 64) {
#pragma unroll
    for (int k2 = 0; k2 < 4; k2++) {
      int c = k2 * 256 + tid;
      int row = c >> 3, c8 = (c & 7) ^ (row & 7);
      GLOAD_LDS16(A + (size_t)(bm + row) * K + k0 + c8 * 8, (char*)sA + c * 16);
      GLOAD_LDS16(B + (size_t)(bn + row) * K + k0 + c8 * 8, (char*)sB + c * 16);
    }
    __syncthreads();
    bf16x8 af[4][2], bfr[4][2];
#pragma unroll
    for (int mt = 0; mt < 4; mt++)
#pragma unroll
      for (int kh = 0; kh < 2; kh++) {
        int ra = wm + mt * 16 + l16;
        af[mt][kh] = *(const bf16x8*)&sA[ra * 64 + (((kh * 4 + quad) ^ (ra & 7)) * 8)];
        int rb = wn + mt * 16 + l16;
        bfr[mt][kh] = *(const bf16x8*)&sB[rb * 64 + (((kh * 4 + quad) ^ (rb & 7)) * 8)];
      }
#pragma unroll
    for (int mt = 0; mt < 4; mt++)
#pragma unroll
      for (int nt = 0; nt < 4; nt++) {
        acc[mt][nt] = __builtin_amdgcn_mfma_f32_16x16x32_bf16(af[mt][0], bfr[nt][0], acc[mt][nt], 0, 0, 0);
        acc[mt][nt] = __builtin_amdgcn_mfma_f32_16x16x32_bf16(af[mt][1], bfr[nt][1], acc[mt][nt], 0, 0, 0);
      }
    __syncthreads();
  }

  if (blockIdx.x < 16) {
    // Q gets 1/sqrt(d_k) * log2(e) folded in (softmax uses exp2)
    const float qs = (blockIdx.x < 8) ? 0.18033688011f : 1.0f;
#pragma unroll
    for (int mt = 0; mt < 4; mt++)
#pragma unroll
      for (int nt = 0; nt < 4; nt++)
#pragma unroll
        for (int r = 0; r < 4; r++) {
          int row = bm + wm + mt * 16 + quad * 4 + r;
          int col = bn + wn + nt * 16 + l16;
          QKb[(size_t)row * 2048 + col] = f2bf(acc[mt][nt][r] * qs);
        }
  } else {
#pragma unroll
    for (int mt = 0; mt < 4; mt++)
#pragma unroll
      for (int nt = 0; nt < 4; nt++) {
        int hd = (bn - 2048) + wn + nt * 16 + l16;
        int tok = bm + wm + mt * 16 + quad * 4;
        ushort4 o;
        o.x = f2bf(acc[mt][nt][0]);
        o.y = f2bf(acc[mt][nt][1]);
        o.z = f2bf(acc[mt][nt][2]);
        o.w = f2bf(acc[mt][nt][3]);
        *(ushort4*)&Vt[(size_t)hd * 4096 + tok] = o;
      }
  }
}

// ---------------------------------------------------------------- flash attention
// 256-thread blocks (4 waves), BQ=128, 32 q-rows/wave (R8's proven per-wave
// structure). Grid 512 -> 2 blocks/CU but 8 waves/CU (vs R8's 5.6), and KV
// staging per CU halves. Q staged into the sK1/sV1 dbuf halves, hoisted, then
// the buffers are recycled. LDS = 32 KB. lsum in VALU + one final shuffle.
__global__ __launch_bounds__(256, 2) void attn_fwd(const u16* __restrict__ QKb,
                                                   const u16* __restrict__ Vt,
                                                   u16* __restrict__ O) {
  const int bx = blockIdx.x;
  const int qt = bx >> 5;         // 0..15 (BQ=128)
  const int h  = (bx >> 1) & 15;
  const int b  = bx & 1;
  const int tid = threadIdx.x;    // 0..255
  const int lane = tid & 63;
  const int wave = tid >> 6;      // 0..3
  const int quad = lane >> 4, l16 = lane & 15;

  // 32 KB: sK0|sK1|sV0|sV1 (8 KB each). Q (16 KB) staged into sK1+sV1 pre-loop.
  __shared__ __align__(16) u16 smem[16384];
  u16* sK0 = smem;
  u16* sK1 = smem + 4096;
  u16* sV0 = smem + 8192;
  u16* sV1 = smem + 12288;

  const int tok0 = b * 2048;
  const int q0 = qt * 128;
  const int colh = h * 64;

  // ---- stage Q rows 0..63 -> sK1, rows 64..127 -> sV1; K0 -> sK0; V0 -> sV0
#pragma unroll
  for (int k2 = 0; k2 < 2; k2++) {
    int c = k2 * 256 + tid;
    int row = c >> 3, c8 = (c & 7) ^ (row & 7);
    GLOAD_LDS16(QKb + (size_t)(tok0 + q0 + row) * 2048 + colh + c8 * 8,
                (char*)sK1 + c * 16);
    GLOAD_LDS16(QKb + (size_t)(tok0 + q0 + 64 + row) * 2048 + colh + c8 * 8,
                (char*)sV1 + c * 16);
    GLOAD_LDS16(QKb + (size_t)(tok0 + row) * 2048 + 1024 + colh + c8 * 8,
                (char*)sK0 + c * 16);
    GLOAD_LDS16(Vt + (size_t)(colh + row) * 4096 + tok0 + c8 * 8,
                (char*)sV0 + c * 16);
  }
  __syncthreads();

  // ---- hoist Q fragments: this wave's 32 q rows (2 subs of 16)
  // waves 0,1 read sK1 (rows 0..63), waves 2,3 read sV1 (rows 64..127)
  const u16* qreg = (wave < 2) ? sK1 : sV1;
  bf16x8 aq[2][2];
#pragma unroll
  for (int sub = 0; sub < 2; sub++)
#pragma unroll
    for (int kh = 0; kh < 2; kh++) {
      int r64 = (wave & 1) * 32 + sub * 16 + l16;
      aq[sub][kh] = *(const bf16x8*)&qreg[r64 * 64 + (((kh * 4 + quad) ^ (r64 & 7)) * 8)];
    }
  __syncthreads();   // all aq reads done before iter-0 prefetch overwrites sK1/sV1

  f32x4 oacc[2][4];
  float lsum[2] = {0.f, 0.f};
#pragma unroll
  for (int sub = 0; sub < 2; sub++)
#pragma unroll
    for (int db = 0; db < 4; db++) oacc[sub][db] = (f32x4){0.f, 0.f, 0.f, 0.f};

  int p = 0;
  for (int it = 0; it < 32; ++it) {
    u16* sKc = p ? sK1 : sK0;
    u16* sVc = p ? sV1 : sV0;
    if (it < 31) {
      u16* sKn = p ? sK0 : sK1;
      u16* sVn = p ? sV0 : sV1;
      const int nkv = (it + 1) * 64;
#pragma unroll
      for (int k2 = 0; k2 < 2; k2++) {
        int c = k2 * 256 + tid;
        int row = c >> 3, c8 = (c & 7) ^ (row & 7);
        GLOAD_LDS16(QKb + (size_t)(tok0 + nkv + row) * 2048 + 1024 + colh + c8 * 8,
                    (char*)sKn + c * 16);
        GLOAD_LDS16(Vt + (size_t)(colh + row) * 4096 + tok0 + nkv + c8 * 8,
                    (char*)sVn + c * 16);
      }
    }

    // K fragments (A-op of S^T: m=kv), b128 — shared by both subs
    bf16x8 kf[4][2];
#pragma unroll
    for (int nt = 0; nt < 4; nt++)
#pragma unroll
      for (int kh = 0; kh < 2; kh++) {
        int rr = nt * 16 + l16;
        kf[nt][kh] = *(const bf16x8*)&sKc[rr * 64 + (((kh * 4 + quad) ^ (rr & 7)) * 8)];
      }
    // V fragments (A-op of PV, K=16: m=d=l16, k=quad*4+i), in-lane b64 reads — shared
    s16x4 vf[4][4];
#pragma unroll
    for (int db = 0; db < 4; db++)
#pragma unroll
      for (int nt = 0; nt < 4; nt++) {
        int row = db * 16 + l16;
        int c16 = (nt * 2 + (quad >> 1)) ^ (row & 7);
        vf[db][nt] = *(const s16x4*)&sVc[row * 64 + c16 * 8 + (quad & 1) * 4];
      }

#pragma unroll
    for (int sub = 0; sub < 2; sub++) {
      // S^T = K Q^T : C rows = kv (nt*16+quad*4+r), cols = q (l16)
      float e[4][4];
#pragma unroll
      for (int nt = 0; nt < 4; nt++) {
        f32x4 c = (f32x4){0.f, 0.f, 0.f, 0.f};
        c = __builtin_amdgcn_mfma_f32_16x16x32_bf16(kf[nt][0], aq[sub][0], c, 0, 0, 0);
        c = __builtin_amdgcn_mfma_f32_16x16x32_bf16(kf[nt][1], aq[sub][1], c, 0, 0, 0);
#pragma unroll
        for (int r = 0; r < 4; r++) e[nt][r] = __builtin_amdgcn_exp2f(c[r]);
        lsum[sub] += (e[nt][0] + e[nt][1]) + (e[nt][2] + e[nt][3]);
      }
      // PV: O^T += V^T P^T. K=16 B-layout == 16x16 C-layout -> pure in-lane pack.
#pragma unroll
      for (int nt = 0; nt < 4; nt++) {
        union { uint32_t u[2]; s16x4 v; } bb;
        bb.u[0] = pkbf(e[nt][0], e[nt][1]);
        bb.u[1] = pkbf(e[nt][2], e[nt][3]);
#pragma unroll
        for (int db = 0; db < 4; db++)
          oacc[sub][db] = __builtin_amdgcn_mfma_f32_16x16x16bf16_1k(vf[db][nt], bb.v, oacc[sub][db], 0, 0, 0);
      }
    }
    __syncthreads();   // buf p consumed by all waves; prefetch into p^1 drained
    p ^= 1;
  }

  // ---- lsum reduce across quads (lane holds q = sub*16 + l16)
#pragma unroll
  for (int sub = 0; sub < 2; sub++) {
    float v = lsum[sub];
    v += __shfl_xor(v, 16, 64);
    v += __shfl_xor(v, 32, 64);
    lsum[sub] = 1.0f / v;
  }

  // ---- epilogue: O^T regs -> per-wave LDS tile [32 q][stride 68] -> coalesced store
  u16* sT = smem + wave * 2176;
#pragma unroll
  for (int sub = 0; sub < 2; sub++)
#pragma unroll
    for (int db = 0; db < 4; db++)
#pragma unroll
      for (int r = 0; r < 4; r++)
        sT[(sub * 16 + l16) * 68 + db * 16 + quad * 4 + r] = f2bf(oacc[sub][db][r] * lsum[sub]);
  // wave-local RAW; compiler orders via lgkmcnt
#pragma unroll
  for (int k = 0; k < 4; k++) {
    int qrow = k * 8 + (lane >> 3);
    int cch = lane & 7;
    uint4 vrow = *(const uint4*)&sT[qrow * 68 + cch * 8];
    int tokr = tok0 + q0 + wave * 32 + qrow;
    *(uint4*)&O[(size_t)tokr * 1024 + colh + cch * 8] = vrow;
  }
}

// ---------------------------------------------------------------- final projection
// 128x64 tiles, BK=64 swizzled. A: O [4096x1024] bf16, B: wo [1024x1024] bf16.
__global__ __launch_bounds__(256) void gemm_out(const u16* __restrict__ A,
                                                const u16* __restrict__ B,
                                                float* __restrict__ C) {
  const int N = 1024, K = 1024;
  __shared__ __align__(16) u16 sA[128 * 64];
  __shared__ __align__(16) u16 sB[64 * 64];
  const int tid = threadIdx.x;
  const int lane = tid & 63;
  const int wave = tid >> 6;
  const int quad = lane >> 4, l16 = lane & 15;
  const int wm = (wave >> 1) * 64, wn = (wave & 1) * 32;
  const int bm = blockIdx.y * 128, bn = blockIdx.x * 64;

  f32x4 acc[4][2];
#pragma unroll
  for (int i = 0; i < 4; i++)
#pragma unroll
    for (int j = 0; j < 2; j++) acc[i][j] = (f32x4){0.f, 0.f, 0.f, 0.f};

  for (int k0 = 0; k0 < K; k0 += 64) {
#pragma unroll
    for (int k2 = 0; k2 < 4; k2++) {
      int c = k2 * 256 + tid;
      int row = c >> 3, c8 = (c & 7) ^ (row & 7);
      GLOAD_LDS16(A + (size_t)(bm + row) * K + k0 + c8 * 8, (char*)sA + c * 16);
    }
#pragma unroll
    for (int k2 = 0; k2 < 2; k2++) {
      int c = k2 * 256 + tid;
      int row = c >> 3, c8 = (c & 7) ^ (row & 7);
      GLOAD_LDS16(B + (size_t)(bn + row) * K + k0 + c8 * 8, (char*)sB + c * 16);
    }
    __syncthreads();
    bf16x8 af[4][2], bfr[2][2];
#pragma unroll
    for (int mt = 0; mt < 4; mt++)
#pragma unroll
      for (int kh = 0; kh < 2; kh++) {
        int ra = wm + mt * 16 + l16;
        af[mt][kh] = *(const bf16x8*)&sA[ra * 64 + (((kh * 4 + quad) ^ (ra & 7)) * 8)];
      }
#pragma unroll
    for (int nt = 0; nt < 2; nt++)
#pragma unroll
      for (int kh = 0; kh < 2; kh++) {
        int rb = wn + nt * 16 + l16;
        bfr[nt][kh] = *(const bf16x8*)&sB[rb * 64 + (((kh * 4 + quad) ^ (rb & 7)) * 8)];
      }
#pragma unroll
    for (int mt = 0; mt < 4; mt++)
#pragma unroll
      for (int nt = 0; nt < 2; nt++) {
        acc[mt][nt] = __builtin_amdgcn_mfma_f32_16x16x32_bf16(af[mt][0], bfr[nt][0], acc[mt][nt], 0, 0, 0);
        acc[mt][nt] = __builtin_amdgcn_mfma_f32_16x16x32_bf16(af[mt][1], bfr[nt][1], acc[mt][nt], 0, 0, 0);
      }
    __syncthreads();
  }

#pragma unroll
  for (int mt = 0; mt < 4; mt++)
#pragma unroll
    for (int nt = 0; nt < 2; nt++)
#pragma unroll
      for (int r = 0; r < 4; r++) {
        int row = bm + wm + mt * 16 + quad * 4 + r;
        int col = bn + wn + nt * 16 + l16;
        C[(size_t)row * N + col] = acc[mt][nt][r];
      }
}

// ---------------------------------------------------------------- launch
extern "C" void kernel_launch(void* const* d_in, const int* in_sizes, int n_in,
                              void* d_out, int out_size, void* d_ws, size_t ws_size,
                              hipStream_t stream) {
  const float* x  = (const float*)d_in[0];
  const float* wq = (const float*)d_in[1];
  const float* wk = (const float*)d_in[2];
  const float* wv = (const float*)d_in[3];
  const float* wo = (const float*)d_in[4];
  float* out = (float*)d_out;
  char* ws = (char*)d_ws;
  const size_t MB = 1u << 20;

  u16* xb    = (u16*)(ws);            // 8 MB  [4096 x 1024] bf16 x
  u16* wqkvb = (u16*)(ws + 8 * MB);   // 6 MB  [3072 x 1024]
  u16* wob   = (u16*)(ws + 14 * MB);  // 2 MB
  u16* QKb   = (u16*)(ws + 16 * MB);  // 16 MB [4096 x 2048] (Q*s | K)
  u16* Vtb   = (u16*)(ws + 32 * MB);  // 8 MB  [1024 hd x 4096 tok]
  u16* Ob    = xb;                    // alias: x dead after QKV gemm

  cvt_all<<<8192, 256, 0, stream>>>(x, wq, wk, wv, wo, xb, wqkvb, wob);

  gemm_qkv<<<dim3(24, 32), 256, 0, stream>>>(xb, wqkvb, QKb, Vtb);

  attn_fwd<<<512, 256, 0, stream>>>(QKb, Vtb, Ob);

  gemm_out<<<dim3(16, 32), 256, 0, stream>>>(Ob, wob, out);
}